// Round 14
// baseline (223.957 us; speedup 1.0000x reference)
//
#include <hip/hip_runtime.h>
#include <math.h>

#define D2 50
#define D3 15
#define D5 10
#define NC 6
#define SCAN_B 512

typedef _Float16 h2 __attribute__((ext_vector_type(2)));
typedef _Float16 f16x8 __attribute__((ext_vector_type(8)));
typedef float    f32x4 __attribute__((ext_vector_type(4)));

// ---------------------------------------------------------------------------
// Kernel A: degree + rank (one int atomic per edge). Block 0 also builds the
// 12 MFMA B-fragment weight tiles (f16) in workspace:
//  t0..3  : edge-L1  (K=32 pad of 9)  x N-tiles 0..3 (N=50 pad 64)
//  t4..5  : edge-L2  K-chunks 0,1 (K=50 pad 64) x N=15 pad 16
//  t6..9  : node-L1  (K=32; k0..14=e2 -> nw1 row 3+k, k15..17=xc -> nw1 row k-15)
//  t10..11: node-L2  K-chunks 0,1
// Element order: tile t, lane l (col=l&15, grp=l>>4), elem i: k = grp*8+i.
// A-fragments use the same convention, so the k-order cancels.
// ---------------------------------------------------------------------------
__global__ __launch_bounds__(256) void deg_rank_prep_kernel(
    const int* __restrict__ ei, int* __restrict__ deg, int* __restrict__ rank, int E,
    const float* __restrict__ ew1, const float* __restrict__ nw1,
    const float* __restrict__ ew2, const float* __restrict__ nw2,
    _Float16* __restrict__ wBf)
{
    int e = blockIdx.x * blockDim.x + threadIdx.x;
    if (e < E) {
        int r = ei[e];
        rank[e] = atomicAdd(&deg[r], 1);
    }
    if (blockIdx.x == 0) {
        for (int q = threadIdx.x; q < 12 * 64 * 8; q += 256) {
            int i = q & 7;
            int l = (q >> 3) & 63;
            int t = q >> 9;
            int col = l & 15, grp = l >> 4;
            int k = grp * 8 + i;
            float v = 0.0f;
            if (t < 4) {
                int n = t * 16 + col;
                if (k < 9 && n < D2) v = ew1[k * D2 + n];
            } else if (t < 6) {
                int kk = (t - 4) * 32 + k;
                if (kk < D2 && col < D3) v = ew2[kk * D3 + col];
            } else if (t < 10) {
                int n = (t - 6) * 16 + col;
                if (n < D2) {
                    if (k < 15)      v = nw1[(3 + k) * D2 + n];
                    else if (k < 18) v = nw1[(k - 15) * D2 + n];
                }
            } else {
                int kk = (t - 10) * 32 + k;
                if (kk < D2 && col < D3) v = nw2[kk * D3 + col];
            }
            wBf[q] = (_Float16)v;
        }
    }
}

// ---------------------------------------------------------------------------
// Scan phase 1: per-block inclusive scan of deg -> exclusive base + block sums.
// ---------------------------------------------------------------------------
__global__ __launch_bounds__(SCAN_B) void scan1_kernel(
    const int* __restrict__ deg, int* __restrict__ base, int* __restrict__ bsum, int N)
{
    __shared__ int sm[SCAN_B];
    int i = blockIdx.x * SCAN_B + threadIdx.x;
    int v = (i < N) ? deg[i] : 0;
    sm[threadIdx.x] = v;
    __syncthreads();
    #pragma unroll
    for (int s = 1; s < SCAN_B; s <<= 1) {
        int t = (threadIdx.x >= (unsigned)s) ? sm[threadIdx.x - s] : 0;
        __syncthreads();
        sm[threadIdx.x] += t;
        __syncthreads();
    }
    if (i < N) base[i] = sm[threadIdx.x] - v;   // exclusive
    if (threadIdx.x == SCAN_B - 1) bsum[blockIdx.x] = sm[threadIdx.x];
}

// ---------------------------------------------------------------------------
// Scan phase 2+3 fused: each block sums bsum[0..bid) itself, adds to base.
// ---------------------------------------------------------------------------
__global__ __launch_bounds__(SCAN_B) void scan23_kernel(
    int* __restrict__ base, const int* __restrict__ bsum, int N)
{
    int bid = blockIdx.x;
    int sum = 0;
    for (int t = (int)threadIdx.x; t < bid; t += SCAN_B) sum += bsum[t];
    #pragma unroll
    for (int s = 32; s > 0; s >>= 1) sum += __shfl_down(sum, s);
    __shared__ int ws[SCAN_B / 64];
    __shared__ int s_total;
    int lane = threadIdx.x & 63, wid = threadIdx.x >> 6;
    if (lane == 0) ws[wid] = sum;
    __syncthreads();
    if (threadIdx.x == 0) {
        int tot = 0;
        #pragma unroll
        for (int w = 0; w < SCAN_B / 64; ++w) tot += ws[w];
        s_total = tot;
    }
    __syncthreads();
    int i = bid * SCAN_B + threadIdx.x;
    if (i < N) base[i] += s_total;
}

// ---------------------------------------------------------------------------
// Kernel C (NEW): MFMA edge+node MLP. One wave = 16 edges per iteration.
// 12 x mfma_f32_16x16x32_f16 per iteration; layers chained through a
// per-wave-private LDS transpose buffer (stride 72 f16 = 144B: 16B-aligned
// b128 reads, 2-way bank aliasing = free). Weights preloaded as B-fragments.
// Biases ride in the accumulator init. Output format = hbuf16 (unchanged).
// ---------------------------------------------------------------------------
__global__ __launch_bounds__(256) void edge_mlp_mfma_kernel(
    const float* __restrict__ x,
    const int*   __restrict__ ei,
    const float* __restrict__ ea,
    const f16x8* __restrict__ wB,      // [12][64]
    const float* __restrict__ eb1, const float* __restrict__ eb2,
    const float* __restrict__ nb1, const float* __restrict__ nb2,
    const int* __restrict__ base, const int* __restrict__ rank,
    unsigned int* __restrict__ hbuf16,
    int E, int ngroups)
{
    __shared__ _Float16 tr[4][16][72];
    __shared__ int slotbuf[4][16];

    int tid  = threadIdx.x;
    int lane = tid & 63;
    int wid  = tid >> 6;
    int col  = lane & 15;
    int grp  = lane >> 4;

    // preload the 12 weight B-fragments (16B each)
    f16x8 wf[12];
    #pragma unroll
    for (int t = 0; t < 12; ++t) wf[t] = wB[t * 64 + lane];

    // per-lane biases (by output column)
    float be1v[4], bn1v[4];
    #pragma unroll
    for (int t = 0; t < 4; ++t) {
        int n = t * 16 + col;
        be1v[t] = (n < D2) ? eb1[n] : 0.0f;
        bn1v[t] = (n < D2) ? nb1[n] : 0.0f;
    }
    float be2v = (col < D3) ? eb2[col] : 0.0f;
    float bn2v = (col < D3) ? nb2[col] : 0.0f;

    int gw = blockIdx.x * 4 + wid;
    int nw = gridDim.x * 4;

    for (int g = gw; g < ngroups; g += nw) {
        int e0 = g * 16;
        int e  = e0 + col;
        int ec = (e < E) ? e : (E - 1);

        // ---- input stage: groups 0,1 build the layer-1 A-fragment ----
        f16x8 a1;
        #pragma unroll
        for (int i = 0; i < 8; ++i) a1[i] = (_Float16)0.0f;
        float xc0 = 0.0f, xc1 = 0.0f, xc2 = 0.0f;

        if (grp == 0) {
            int r = ei[ec], c = ei[E + ec];
            slotbuf[wid][col] = (e < E) ? (base[r] + rank[ec]) : -1;
            float xr0 = x[3 * r], xr1 = x[3 * r + 1], xr2 = x[3 * r + 2];
            xc0 = x[3 * c]; xc1 = x[3 * c + 1]; xc2 = x[3 * c + 2];
            float ea0 = ea[3 * (size_t)ec], ea1 = ea[3 * (size_t)ec + 1];
            a1[0] = (_Float16)xr0; a1[1] = (_Float16)xr1; a1[2] = (_Float16)xr2;
            a1[3] = (_Float16)xc0; a1[4] = (_Float16)xc1; a1[5] = (_Float16)xc2;
            a1[6] = (_Float16)ea0; a1[7] = (_Float16)ea1;
        } else if (grp == 1) {
            a1[0] = (_Float16)ea[3 * (size_t)ec + 2];
        }

        // ---- edge L1: in9(pad32) x 50(pad64), 4 N-tiles ----
        f32x4 hacc[4];
        #pragma unroll
        for (int t = 0; t < 4; ++t) {
            f32x4 cin = {be1v[t], be1v[t], be1v[t], be1v[t]};
            hacc[t] = __builtin_amdgcn_mfma_f32_16x16x32_f16(a1, wf[t], cin, 0, 0, 0);
        }
        // relu + write h to tr[edge][0..63] (cols >= 50 write 0)
        #pragma unroll
        for (int t = 0; t < 4; ++t) {
            int n = t * 16 + col;
            #pragma unroll
            for (int r2 = 0; r2 < 4; ++r2) {
                int eidx = grp * 4 + r2;
                float v = (n < D2) ? fmaxf(hacc[t][r2], 0.0f) : 0.0f;
                tr[wid][eidx][n] = (_Float16)v;
            }
        }

        // ---- edge L2: h50(pad64) x 15(pad16), 2 K-chunks ----
        f16x8 alo = *(const f16x8*)&tr[wid][col][grp * 8];
        f16x8 ahi = *(const f16x8*)&tr[wid][col][32 + grp * 8];
        f32x4 e2acc = {be2v, be2v, be2v, be2v};
        e2acc = __builtin_amdgcn_mfma_f32_16x16x32_f16(alo, wf[4], e2acc, 0, 0, 0);
        e2acc = __builtin_amdgcn_mfma_f32_16x16x32_f16(ahi, wf[5], e2acc, 0, 0, 0);

        // write node-L1 input: [0..14]=e2, [15..17]=xc, [18..31]=0
        #pragma unroll
        for (int r2 = 0; r2 < 4; ++r2) {
            int eidx = grp * 4 + r2;
            if (col < D3) tr[wid][eidx][col] = (_Float16)e2acc[r2];
        }
        if (grp == 0) {
            tr[wid][col][15] = (_Float16)xc0;
            tr[wid][col][16] = (_Float16)xc1;
            tr[wid][col][17] = (_Float16)xc2;
        }
        #pragma unroll
        for (int pass = 0; pass < 2; ++pass) {
            int zz = lane + pass * 64;
            if (zz < 112) {
                int eidx = zz / 7, sl = zz % 7;
                *((unsigned int*)&tr[wid][eidx][18 + sl * 2]) = 0u;
            }
        }

        // ---- node L1: in18(pad32) x 50(pad64), 4 N-tiles ----
        f16x8 an = *(const f16x8*)&tr[wid][col][grp * 8];
        f32x4 h2acc[4];
        #pragma unroll
        for (int t = 0; t < 4; ++t) {
            f32x4 cin = {bn1v[t], bn1v[t], bn1v[t], bn1v[t]};
            h2acc[t] = __builtin_amdgcn_mfma_f32_16x16x32_f16(an, wf[6 + t], cin, 0, 0, 0);
        }
        #pragma unroll
        for (int t = 0; t < 4; ++t) {
            int n = t * 16 + col;
            #pragma unroll
            for (int r2 = 0; r2 < 4; ++r2) {
                int eidx = grp * 4 + r2;
                float v = (n < D2) ? fmaxf(h2acc[t][r2], 0.0f) : 0.0f;
                tr[wid][eidx][n] = (_Float16)v;
            }
        }

        // ---- node L2: h50(pad64) x 15(pad16), 2 K-chunks ----
        alo = *(const f16x8*)&tr[wid][col][grp * 8];
        ahi = *(const f16x8*)&tr[wid][col][32 + grp * 8];
        f32x4 oacc = {bn2v, bn2v, bn2v, bn2v};
        oacc = __builtin_amdgcn_mfma_f32_16x16x32_f16(alo, wf[10], oacc, 0, 0, 0);
        oacc = __builtin_amdgcn_mfma_f32_16x16x32_f16(ahi, wf[11], oacc, 0, 0, 0);

        // stage output tile [edge][0..15] (col 15 = pad 0)
        #pragma unroll
        for (int r2 = 0; r2 < 4; ++r2) {
            int eidx = grp * 4 + r2;
            if (col < D3) tr[wid][eidx][col] = (_Float16)oacc[r2];
            else          tr[wid][eidx][15]  = (_Float16)0.0f;
        }

        // 32B store per edge (2 x 16B by lanes 0..31)
        if (lane < 32) {
            int eidx = lane >> 1, half = lane & 1;
            int slot = slotbuf[wid][eidx];
            if (slot >= 0) {
                uint4 v = *(const uint4*)&tr[wid][eidx][half * 8];
                *(uint4*)(hbuf16 + (size_t)slot * 8 + half * 4) = v;
            }
        }
    }
}

// ---------------------------------------------------------------------------
// Kernel T: fused tail (round-9/13 proven version). One block per graph.
// ---------------------------------------------------------------------------
__global__ __launch_bounds__(256) void tail_kernel(
    const unsigned int* __restrict__ hbuf16,
    const int* __restrict__ deg, const int* __restrict__ base,
    const int* __restrict__ batch, int N,
    const float* __restrict__ u,
    const float* __restrict__ gw1, const float* __restrict__ gb1,
    const float* __restrict__ gw2, const float* __restrict__ gb2,
    const float* __restrict__ fc1w, const float* __restrict__ fc1b,
    const float* __restrict__ bng, const float* __restrict__ bnb,
    const float* __restrict__ fc2w, const float* __restrict__ fc2b,
    float* __restrict__ out)
{
    int b = blockIdx.x;
    int tid = threadIdx.x;

    int lo = 0, hi = N;
    while (lo < hi) { int m = (lo + hi) >> 1; if (batch[m] < b) lo = m + 1; else hi = m; }
    int start = lo;
    hi = N;
    while (lo < hi) { int m = (lo + hi) >> 1; if (batch[m] < b + 1) lo = m + 1; else hi = m; }
    int end = lo;

    float sx[D3], sr[D3];
    #pragma unroll
    for (int j = 0; j < D3; ++j) { sx[j] = 0.0f; sr[j] = 0.0f; }

    for (int i = start + tid; i < end; i += 256) {
        int bs = base[i];
        int d  = deg[i];
        float acc[16];
        #pragma unroll
        for (int j = 0; j < 16; ++j) acc[j] = 0.0f;
        const uint4* ptr = (const uint4*)(hbuf16 + (size_t)bs * 8);
        for (int k = 0; k < d; ++k) {
            uint4 w0 = ptr[2 * k];
            uint4 w1 = ptr[2 * k + 1];
            unsigned int ws[8] = {w0.x, w0.y, w0.z, w0.w, w1.x, w1.y, w1.z, w1.w};
            #pragma unroll
            for (int p = 0; p < 8; ++p) {
                h2 v = __builtin_bit_cast(h2, ws[p]);
                acc[2 * p]     += (float)v[0];
                acc[2 * p + 1] += (float)v[1];
            }
        }
        float inv = 1.0f / fmaxf((float)d, 1.0f);
        #pragma unroll
        for (int j = 0; j < D3; ++j) {
            float v = acc[j] * inv;
            sx[j] += v;
            sr[j] += fmaxf(v, 0.0f);
        }
    }

    #pragma unroll
    for (int j = 0; j < D3; ++j) {
        #pragma unroll
        for (int s = 32; s > 0; s >>= 1) {
            sx[j] += __shfl_down(sx[j], s);
            sr[j] += __shfl_down(sr[j], s);
        }
    }

    __shared__ float sm[4][2 * D3];
    __shared__ float s_red[2 * D3];
    __shared__ float s_in16[16];
    __shared__ float s_gh[D2];
    __shared__ float s_g[D3];
    __shared__ float s_h1[D5];

    int lane = tid & 63, wid = tid >> 6;
    if (lane == 0) {
        #pragma unroll
        for (int j = 0; j < D3; ++j) { sm[wid][j] = sx[j]; sm[wid][D3 + j] = sr[j]; }
    }
    __syncthreads();

    float nct = (float)(end - start);

    if (tid < 2 * D3) {
        s_red[tid] = sm[0][tid] + sm[1][tid] + sm[2][tid] + sm[3][tid];
    }
    __syncthreads();

    if (tid < 16) {
        s_in16[tid] = (tid == 0) ? u[b] : s_red[tid - 1] / fmaxf(nct, 1.0f);
    }
    __syncthreads();

    if (tid < D2) {
        float a = gb1[tid];
        #pragma unroll
        for (int k = 0; k < 16; ++k) a = fmaf(s_in16[k], gw1[k * D2 + tid], a);
        s_gh[tid] = fmaxf(a, 0.0f);
    }
    __syncthreads();

    if (tid < D3) {
        float a = gb2[tid];
        #pragma unroll
        for (int k = 0; k < D2; ++k) a = fmaf(s_gh[k], gw2[k * D3 + tid], a);
        s_g[tid] = (s_red[D3 + tid] + fmaxf(a, 0.0f)) / (nct + 1.0f);
    }
    __syncthreads();

    if (tid < D5) {
        const float bnscale = 1.0f / sqrtf(1.0f + 1e-5f);
        float a = fc1b[tid];
        #pragma unroll
        for (int k = 0; k < D3; ++k) a = fmaf(s_g[k], fc1w[k * D5 + tid], a);
        s_h1[tid] = fmaxf(a * (bng[tid] * bnscale) + bnb[tid], 0.0f);
    }
    __syncthreads();

    if (tid == 0) {
        float o[NC];
        #pragma unroll
        for (int j = 0; j < NC; ++j) {
            float a = fc2b[j];
            #pragma unroll
            for (int k = 0; k < D5; ++k) a = fmaf(s_h1[k], fc2w[k * NC + j], a);
            o[j] = a;
        }
        float m = o[0];
        #pragma unroll
        for (int j = 1; j < NC; ++j) m = fmaxf(m, o[j]);
        float ssum = 0.0f;
        #pragma unroll
        for (int j = 0; j < NC; ++j) ssum += expf(o[j] - m);
        float lse = m + logf(ssum);
        #pragma unroll
        for (int j = 0; j < NC; ++j) out[b * NC + j] = o[j] - lse;
    }
}

// ---------------------------------------------------------------------------
// Fallback (round-1) kernels: atomic scatter-mean. Used only if ws too small.
// ---------------------------------------------------------------------------
__global__ __launch_bounds__(256) void edge_node_atomic_kernel(
    const float* __restrict__ x,
    const int*   __restrict__ ei,
    const float* __restrict__ ea,
    const float* __restrict__ ew1, const float* __restrict__ eb1,
    const float* __restrict__ ew2, const float* __restrict__ eb2,
    const float* __restrict__ nw1, const float* __restrict__ nb1,
    const float* __restrict__ nw2, const float* __restrict__ nb2,
    float* __restrict__ x2sum, float* __restrict__ cnt,
    int E)
{
    int e = blockIdx.x * blockDim.x + threadIdx.x;
    if (e >= E) return;
    int r = ei[e];
    int c = ei[E + e];
    float in9[9];
    in9[0] = x[3 * r + 0]; in9[1] = x[3 * r + 1]; in9[2] = x[3 * r + 2];
    float xc0 = x[3 * c + 0], xc1 = x[3 * c + 1], xc2 = x[3 * c + 2];
    in9[3] = xc0; in9[4] = xc1; in9[5] = xc2;
    in9[6] = ea[3 * e + 0]; in9[7] = ea[3 * e + 1]; in9[8] = ea[3 * e + 2];
    float h[D2];
    #pragma unroll
    for (int j = 0; j < D2; ++j) {
        float a = eb1[j];
        #pragma unroll
        for (int k = 0; k < 9; ++k) a = fmaf(in9[k], ew1[k * D2 + j], a);
        h[j] = fmaxf(a, 0.0f);
    }
    float e2[D3];
    #pragma unroll
    for (int j = 0; j < D3; ++j) {
        float a = eb2[j];
        #pragma unroll
        for (int k = 0; k < D2; ++k) a = fmaf(h[k], ew2[k * D3 + j], a);
        e2[j] = a;
    }
    float h2v[D2];
    #pragma unroll
    for (int j = 0; j < D2; ++j) {
        float a = nb1[j];
        a = fmaf(xc0, nw1[0 * D2 + j], a);
        a = fmaf(xc1, nw1[1 * D2 + j], a);
        a = fmaf(xc2, nw1[2 * D2 + j], a);
        #pragma unroll
        for (int k = 0; k < D3; ++k) a = fmaf(e2[k], nw1[(3 + k) * D2 + j], a);
        h2v[j] = fmaxf(a, 0.0f);
    }
    float* dst = x2sum + (size_t)r * D3;
    #pragma unroll
    for (int j = 0; j < D3; ++j) {
        float a = nb2[j];
        #pragma unroll
        for (int k = 0; k < D2; ++k) a = fmaf(h2v[k], nw2[k * D3 + j], a);
        atomicAdd(&dst[j], a);
    }
    atomicAdd(&cnt[r], 1.0f);
}

__global__ __launch_bounds__(256) void graph_sum_atomic_kernel(
    const float* __restrict__ x2sum, const float* __restrict__ cnt,
    const int* __restrict__ batch, int N,
    float* __restrict__ bx, float* __restrict__ brelu, float* __restrict__ ncnt)
{
    int b = blockIdx.x;
    int lo = 0, hi = N;
    while (lo < hi) { int m = (lo + hi) >> 1; if (batch[m] < b) lo = m + 1; else hi = m; }
    int start = lo;
    hi = N;
    while (lo < hi) { int m = (lo + hi) >> 1; if (batch[m] < b + 1) lo = m + 1; else hi = m; }
    int end = lo;
    float sx[D3], sr[D3];
    #pragma unroll
    for (int j = 0; j < D3; ++j) { sx[j] = 0.0f; sr[j] = 0.0f; }
    for (int i = start + (int)threadIdx.x; i < end; i += (int)blockDim.x) {
        float inv = 1.0f / fmaxf(cnt[i], 1.0f);
        #pragma unroll
        for (int j = 0; j < D3; ++j) {
            float v = x2sum[(size_t)i * D3 + j] * inv;
            sx[j] += v;
            sr[j] += fmaxf(v, 0.0f);
        }
    }
    #pragma unroll
    for (int j = 0; j < D3; ++j) {
        #pragma unroll
        for (int s = 32; s > 0; s >>= 1) {
            sx[j] += __shfl_down(sx[j], s);
            sr[j] += __shfl_down(sr[j], s);
        }
    }
    __shared__ float sm[4][2 * D3];
    int lane = threadIdx.x & 63, wid = threadIdx.x >> 6;
    if (lane == 0) {
        #pragma unroll
        for (int j = 0; j < D3; ++j) { sm[wid][j] = sx[j]; sm[wid][D3 + j] = sr[j]; }
    }
    __syncthreads();
    if (threadIdx.x < 2 * D3) {
        float v = sm[0][threadIdx.x] + sm[1][threadIdx.x] + sm[2][threadIdx.x] + sm[3][threadIdx.x];
        if (threadIdx.x < D3) bx[b * D3 + threadIdx.x] = v;
        else                  brelu[b * D3 + (threadIdx.x - D3)] = v;
    }
    if (threadIdx.x == 0) ncnt[b] = (float)(end - start);
}

__global__ __launch_bounds__(256) void final_kernel(
    const float* __restrict__ u,
    const float* __restrict__ gw1, const float* __restrict__ gb1,
    const float* __restrict__ gw2, const float* __restrict__ gb2,
    const float* __restrict__ fc1w, const float* __restrict__ fc1b,
    const float* __restrict__ bng, const float* __restrict__ bnb,
    const float* __restrict__ fc2w, const float* __restrict__ fc2b,
    const float* __restrict__ bx, const float* __restrict__ brelu,
    const float* __restrict__ ncnt,
    float* __restrict__ out, int B)
{
    int t = blockIdx.x * blockDim.x + threadIdx.x;
    if (t >= B) return;
    float nct = ncnt[t];
    float inv = 1.0f / fmaxf(nct, 1.0f);
    float in16[16];
    in16[0] = u[t];
    #pragma unroll
    for (int j = 0; j < D3; ++j) in16[1 + j] = bx[t * D3 + j] * inv;
    float gh[D2];
    #pragma unroll
    for (int j = 0; j < D2; ++j) {
        float a = gb1[j];
        #pragma unroll
        for (int k = 0; k < 16; ++k) a = fmaf(in16[k], gw1[k * D2 + j], a);
        gh[j] = fmaxf(a, 0.0f);
    }
    float g[D3];
    #pragma unroll
    for (int j = 0; j < D3; ++j) {
        float a = gb2[j];
        #pragma unroll
        for (int k = 0; k < D2; ++k) a = fmaf(gh[k], gw2[k * D3 + j], a);
        g[j] = (brelu[t * D3 + j] + fmaxf(a, 0.0f)) / (nct + 1.0f);
    }
    const float bnscale = 1.0f / sqrtf(1.0f + 1e-5f);
    float h1[D5];
    #pragma unroll
    for (int i = 0; i < D5; ++i) {
        float a = fc1b[i];
        #pragma unroll
        for (int k = 0; k < D3; ++k) a = fmaf(g[k], fc1w[k * D5 + i], a);
        h1[i] = fmaxf(a * (bng[i] * bnscale) + bnb[i], 0.0f);
    }
    float o[NC];
    #pragma unroll
    for (int j = 0; j < NC; ++j) {
        float a = fc2b[j];
        #pragma unroll
        for (int k = 0; k < D5; ++k) a = fmaf(h1[k], fc2w[k * NC + j], a);
        o[j] = a;
    }
    float m = o[0];
    #pragma unroll
    for (int j = 1; j < NC; ++j) m = fmaxf(m, o[j]);
    float ssum = 0.0f;
    #pragma unroll
    for (int j = 0; j < NC; ++j) ssum += expf(o[j] - m);
    float lse = m + logf(ssum);
    #pragma unroll
    for (int j = 0; j < NC; ++j) out[t * NC + j] = o[j] - lse;
}

extern "C" void kernel_launch(void* const* d_in, const int* in_sizes, int n_in,
                              void* d_out, int out_size, void* d_ws, size_t ws_size,
                              hipStream_t stream) {
    const float* x     = (const float*)d_in[0];
    const int*   ei    = (const int*)  d_in[1];
    const float* ea    = (const float*)d_in[2];
    const float* u     = (const float*)d_in[3];
    const int*   batch = (const int*)  d_in[4];
    const float* ew1 = (const float*)d_in[5];
    const float* eb1 = (const float*)d_in[6];
    const float* ew2 = (const float*)d_in[7];
    const float* eb2 = (const float*)d_in[8];
    const float* nw1 = (const float*)d_in[9];
    const float* nb1 = (const float*)d_in[10];
    const float* nw2 = (const float*)d_in[11];
    const float* nb2 = (const float*)d_in[12];
    const float* gw1 = (const float*)d_in[13];
    const float* gb1 = (const float*)d_in[14];
    const float* gw2 = (const float*)d_in[15];
    const float* gb2 = (const float*)d_in[16];
    const float* fc1w = (const float*)d_in[17];
    const float* fc1b = (const float*)d_in[18];
    const float* bng  = (const float*)d_in[19];
    const float* bnb  = (const float*)d_in[20];
    const float* fc2w = (const float*)d_in[21];
    const float* fc2b = (const float*)d_in[22];

    int N = in_sizes[0] / 3;
    int E = in_sizes[2] / 3;
    int B = in_sizes[3];
    float* out = (float*)d_out;

    int nsb = (N + SCAN_B - 1) / SCAN_B;
    const size_t WBF = 12 * 64 * 8;        // MFMA weight fragments (f16)

    size_t need = sizeof(_Float16) * WBF
                + sizeof(unsigned int) * (size_t)E * 8                 /* hbuf16 */
                + sizeof(int) * ((size_t)N + (size_t)E + (size_t)N + 1024);

    if (ws_size >= need && nsb <= 1024) {
        // ---- fast path: CSR build + MFMA MLP + fused tail ----
        char* p = (char*)d_ws;
        _Float16* wBf = (_Float16*)p;       p += sizeof(_Float16) * WBF;
        unsigned int* hbuf16 = (unsigned int*)p;  p += sizeof(unsigned int) * (size_t)E * 8;
        int* deg  = (int*)p;            p += sizeof(int) * (size_t)N;
        int* rank = (int*)p;            p += sizeof(int) * (size_t)E;
        int* base = (int*)p;            p += sizeof(int) * (size_t)N;
        int* bsum = (int*)p;            p += sizeof(int) * 1024;

        hipMemsetAsync(deg, 0, sizeof(int) * (size_t)N, stream);

        int eb = (E + 255) / 256;
        deg_rank_prep_kernel<<<eb, 256, 0, stream>>>(
            ei, deg, rank, E, ew1, nw1, ew2, nw2, wBf);

        scan1_kernel<<<nsb, SCAN_B, 0, stream>>>(deg, base, bsum, N);
        scan23_kernel<<<nsb, SCAN_B, 0, stream>>>(base, bsum, N);

        int ngroups = (E + 15) / 16;
        int nb = (ngroups + 3) / 4;
        if (nb > 1024) nb = 1024;
        edge_mlp_mfma_kernel<<<nb, 256, 0, stream>>>(
            x, ei, ea, (const f16x8*)wBf, eb1, eb2, nb1, nb2,
            base, rank, hbuf16, E, ngroups);

        tail_kernel<<<B, 256, 0, stream>>>(
            hbuf16, deg, base, batch, N,
            u, gw1, gb1, gw2, gb2, fc1w, fc1b, bng, bnb, fc2w, fc2b, out);
    } else {
        // ---- fallback: round-1 atomic path (fp32 exact) ----
        float* x2sum = (float*)d_ws;
        float* cnt   = x2sum + (size_t)N * D3;
        float* bx    = cnt + N;
        float* brelu = bx + (size_t)B * D3;
        float* ncnt  = brelu + (size_t)B * D3;

        hipMemsetAsync(x2sum, 0, sizeof(float) * ((size_t)N * D3 + N), stream);

        int eb = (E + 255) / 256;
        edge_node_atomic_kernel<<<eb, 256, 0, stream>>>(
            x, ei, ea, ew1, eb1, ew2, eb2, nw1, nb1, nw2, nb2, x2sum, cnt, E);

        graph_sum_atomic_kernel<<<B, 256, 0, stream>>>(x2sum, cnt, batch, N, bx, brelu, ncnt);

        int fb = (B + 255) / 256;
        final_kernel<<<fb, 256, 0, stream>>>(
            u, gw1, gb1, gw2, gb2, fc1w, fc1b, bng, bnb, fc2w, fc2b,
            bx, brelu, ncnt, out, B);
    }
}